// Round 1
// baseline (316.956 us; speedup 1.0000x reference)
//
#include <hip/hip_runtime.h>

// Problem constants (B, T, V, C) = (256, 2048, 32000, 128)
#define B_ 256
#define T_ 2048
#define V_ 32000
#define C_ 128

// Prep: Wt[v][c] = W[c][v] + bias[c]   (16.4 MB into workspace)
// Standard LDS-tiled 32x32 transpose, +1 pad to kill bank conflicts.
__global__ __launch_bounds__(256) void transpose_bias_kernel(
    const float* __restrict__ W, const float* __restrict__ bias,
    float* __restrict__ Wt) {
    __shared__ float tile[32][33];
    const int v0 = blockIdx.x * 32;   // V_ / 32 = 1000 blocks in x
    const int c0 = blockIdx.y * 32;   // C_ / 32 = 4 blocks in y
    const int tx = threadIdx.x;       // 0..31
    const int ty = threadIdx.y;       // 0..7
#pragma unroll
    for (int i = 0; i < 4; ++i) {
        const int cl = ty + i * 8;
        // coalesced read along v
        tile[cl][tx] = W[(size_t)(c0 + cl) * V_ + v0 + tx];
    }
    __syncthreads();
#pragma unroll
    for (int i = 0; i < 4; ++i) {
        const int vl = ty + i * 8;
        const int c  = c0 + tx;
        // coalesced write along c; fold bias here so main kernel skips it
        Wt[(size_t)(v0 + vl) * C_ + c] = tile[tx][vl] + bias[c];
    }
}

// Main: out[b][c][t] = Wt[idx[b][t]][c]
// Block: one b, a 32-wide t tile. 256 threads:
//   cq = tid>>3 (0..31): which float4 along C (c = 4*cq .. 4*cq+3)
//   tg = tid&7  (0..7) : which group of 4 consecutive t
// Gather: per wave, 8 rows x 128 B contiguous -> full-line coalescing, no over-fetch.
// Store : per store instruction, 8 contiguous 128 B segments -> fully coalesced.
__global__ __launch_bounds__(256) void gather_kernel(
    const int* __restrict__ idx, const float4* __restrict__ Wt4,
    float* __restrict__ out) {
    const int b   = blockIdx.y;
    const int t0  = blockIdx.x * 32;
    const int tid = threadIdx.x;
    const int cq  = tid >> 3;   // 0..31
    const int tg  = tid & 7;    // 0..7
    const int t   = t0 + tg * 4;

    const int4 iv = *(const int4*)(idx + (size_t)b * T_ + t);

    const float4 w0 = Wt4[(size_t)iv.x * (C_ / 4) + cq];
    const float4 w1 = Wt4[(size_t)iv.y * (C_ / 4) + cq];
    const float4 w2 = Wt4[(size_t)iv.z * (C_ / 4) + cq];
    const float4 w3 = Wt4[(size_t)iv.w * (C_ / 4) + cq];

    float* o = out + ((size_t)b * C_ + (size_t)cq * 4) * T_ + t;
    // 4x4 register transpose: component j of w_k -> out[c=4cq+j][t+k]
    *(float4*)(o)           = make_float4(w0.x, w1.x, w2.x, w3.x);
    *(float4*)(o + T_)      = make_float4(w0.y, w1.y, w2.y, w3.y);
    *(float4*)(o + 2 * T_)  = make_float4(w0.z, w1.z, w2.z, w3.z);
    *(float4*)(o + 3 * T_)  = make_float4(w0.w, w1.w, w2.w, w3.w);
}

// Fallback (only if ws_size can't hold Wt): direct gather from original W layout.
__global__ __launch_bounds__(256) void gather_direct_kernel(
    const int* __restrict__ idx, const float* __restrict__ W,
    const float* __restrict__ bias, float* __restrict__ out) {
    const size_t o = (size_t)blockIdx.x * blockDim.x + threadIdx.x; // over B*C*T/4
    const int T4   = T_ / 4;
    const int t4   = (int)(o % T4);
    const int rest = (int)(o / T4);
    const int c    = rest % C_;
    const int b    = rest / C_;
    const int4 iv  = *(const int4*)(idx + (size_t)b * T_ + (size_t)t4 * 4);
    const float* Wr = W + (size_t)c * V_;
    const float bc  = bias[c];
    ((float4*)out)[o] =
        make_float4(Wr[iv.x] + bc, Wr[iv.y] + bc, Wr[iv.z] + bc, Wr[iv.w] + bc);
}

extern "C" void kernel_launch(void* const* d_in, const int* in_sizes, int n_in,
                              void* d_out, int out_size, void* d_ws, size_t ws_size,
                              hipStream_t stream) {
    const int*   idx  = (const int*)d_in[0];    // (B,1,T) int32
    const float* W    = (const float*)d_in[1];  // (C,V) fp32
    const float* bias = (const float*)d_in[2];  // (C,) fp32
    float*       out  = (float*)d_out;          // (B,C,T) fp32

    const size_t wt_bytes = (size_t)V_ * C_ * sizeof(float); // 16.4 MB

    if (ws_size >= wt_bytes) {
        float* Wt = (float*)d_ws;
        transpose_bias_kernel<<<dim3(V_ / 32, C_ / 32), dim3(32, 8), 0, stream>>>(
            W, bias, Wt);
        gather_kernel<<<dim3(T_ / 32, B_), 256, 0, stream>>>(
            idx, (const float4*)Wt, out);
    } else {
        const size_t total = (size_t)B_ * C_ * (T_ / 4);
        gather_direct_kernel<<<(unsigned)((total + 255) / 256), 256, 0, stream>>>(
            idx, W, bias, out);
    }
}

// Round 3
// 305.378 us; speedup vs baseline: 1.0379x; 1.0379x over previous
//
#include <hip/hip_runtime.h>

// Problem constants (B, T, V, C) = (256, 2048, 32000, 128)
#define B_ 256
#define T_ 2048
#define V_ 32000
#define C_ 128

// Native clang vector type — __builtin_nontemporal_* rejects HIP's float4 class.
typedef float v4f __attribute__((ext_vector_type(4)));
typedef int   v4i __attribute__((ext_vector_type(4)));

// Prep: Wt[v][c] = W[c][v] + bias[c]   (16.4 MB into workspace)
// Standard LDS-tiled 32x32 transpose, +1 pad to kill bank conflicts.
// W is read-once -> nontemporal loads (don't pollute L2; Wt must stay hot).
__global__ __launch_bounds__(256) void transpose_bias_kernel(
    const float* __restrict__ W, const float* __restrict__ bias,
    float* __restrict__ Wt) {
    __shared__ float tile[32][33];
    const int v0 = blockIdx.x * 32;   // V_ / 32 = 1000 blocks in x
    const int c0 = blockIdx.y * 32;   // C_ / 32 = 4 blocks in y
    const int tx = threadIdx.x;       // 0..31
    const int ty = threadIdx.y;       // 0..7
#pragma unroll
    for (int i = 0; i < 4; ++i) {
        const int cl = ty + i * 8;
        // coalesced read along v, nontemporal (W never read again)
        tile[cl][tx] = __builtin_nontemporal_load(
            W + (size_t)(c0 + cl) * V_ + v0 + tx);
    }
    __syncthreads();
#pragma unroll
    for (int i = 0; i < 4; ++i) {
        const int vl = ty + i * 8;
        const int c  = c0 + tx;
        // coalesced write along c; cached (gather kernel re-reads Wt ~16x)
        Wt[(size_t)(v0 + vl) * C_ + c] = tile[tx][vl] + bias[c];
    }
}

// Main: out[b][c][t] = Wt[idx[b][t]][c]
// Block: one b, a 32-wide t tile. 256 threads:
//   cq = tid>>3 (0..31): which float4 along C (c = 4*cq .. 4*cq+3)
//   tg = tid&7  (0..7) : which group of 4 consecutive t
// Gather: per wave-instruction, 8 rows x 128 B contiguous segments (full lines).
// Store : NONTEMPORAL — out is write-once; bypassing L2 keeps the 16.4 MB Wt
//         table resident instead of being thrashed by 268 MB of write-allocates.
__global__ __launch_bounds__(256) void gather_kernel(
    const int* __restrict__ idx, const v4f* __restrict__ Wt4,
    float* __restrict__ out) {
    const int b   = blockIdx.y;
    const int t0  = blockIdx.x * 32;
    const int tid = threadIdx.x;
    const int cq  = tid >> 3;   // 0..31
    const int tg  = tid & 7;    // 0..7
    const int t   = t0 + tg * 4;

    const v4i iv = *(const v4i*)(idx + b * T_ + t);

    const v4f w0 = Wt4[iv.x * (C_ / 4) + cq];
    const v4f w1 = Wt4[iv.y * (C_ / 4) + cq];
    const v4f w2 = Wt4[iv.z * (C_ / 4) + cq];
    const v4f w3 = Wt4[iv.w * (C_ / 4) + cq];

    float* o = out + ((size_t)(b * C_ + cq * 4)) * T_ + t;
    // 4x4 register transpose: component j of w_k -> out[c=4cq+j][t+k]
    __builtin_nontemporal_store((v4f){w0.x, w1.x, w2.x, w3.x}, (v4f*)(o));
    __builtin_nontemporal_store((v4f){w0.y, w1.y, w2.y, w3.y}, (v4f*)(o + T_));
    __builtin_nontemporal_store((v4f){w0.z, w1.z, w2.z, w3.z}, (v4f*)(o + 2 * T_));
    __builtin_nontemporal_store((v4f){w0.w, w1.w, w2.w, w3.w}, (v4f*)(o + 3 * T_));
}

// Fallback (only if ws_size can't hold Wt): direct gather from original W layout.
__global__ __launch_bounds__(256) void gather_direct_kernel(
    const int* __restrict__ idx, const float* __restrict__ W,
    const float* __restrict__ bias, float* __restrict__ out) {
    const size_t o = (size_t)blockIdx.x * blockDim.x + threadIdx.x; // over B*C*T/4
    const int T4   = T_ / 4;
    const int t4   = (int)(o % T4);
    const int rest = (int)(o / T4);
    const int c    = rest % C_;
    const int b    = rest / C_;
    const v4i iv   = *(const v4i*)(idx + (size_t)b * T_ + (size_t)t4 * 4);
    const float* Wr = W + (size_t)c * V_;
    const float bc  = bias[c];
    __builtin_nontemporal_store(
        (v4f){Wr[iv.x] + bc, Wr[iv.y] + bc, Wr[iv.z] + bc, Wr[iv.w] + bc},
        ((v4f*)out) + o);
}

extern "C" void kernel_launch(void* const* d_in, const int* in_sizes, int n_in,
                              void* d_out, int out_size, void* d_ws, size_t ws_size,
                              hipStream_t stream) {
    const int*   idx  = (const int*)d_in[0];    // (B,1,T) int32
    const float* W    = (const float*)d_in[1];  // (C,V) fp32
    const float* bias = (const float*)d_in[2];  // (C,) fp32
    float*       out  = (float*)d_out;          // (B,C,T) fp32

    const size_t wt_bytes = (size_t)V_ * C_ * sizeof(float); // 16.4 MB

    if (ws_size >= wt_bytes) {
        float* Wt = (float*)d_ws;
        transpose_bias_kernel<<<dim3(V_ / 32, C_ / 32), dim3(32, 8), 0, stream>>>(
            W, bias, Wt);
        gather_kernel<<<dim3(T_ / 32, B_), 256, 0, stream>>>(
            idx, (const v4f*)Wt, out);
    } else {
        const size_t total = (size_t)B_ * C_ * (T_ / 4);
        gather_direct_kernel<<<(unsigned)((total + 255) / 256), 256, 0, stream>>>(
            idx, W, bias, out);
    }
}